// Round 3
// baseline (3040.296 us; speedup 1.0000x reference)
//
#include <hip/hip_runtime.h>

typedef unsigned short u16;
typedef __attribute__((ext_vector_type(8))) short short8;
typedef __attribute__((ext_vector_type(4))) float f32x4;

__device__ __forceinline__ u16 f2bf(float f) {
  union { float f; unsigned u; } v; v.f = f;
  unsigned r = (v.u + 0x7fffu + ((v.u >> 16) & 1u)) >> 16;
  return (u16)r;
}
__device__ __forceinline__ float sigm(float x) { return 1.f / (1.f + __expf(-x)); }
__device__ __forceinline__ float tanh_(float x) { return 1.f - 2.f / (__expf(2.f * x) + 1.f); }
__device__ __forceinline__ f32x4 mfma16(short8 a, short8 b, f32x4 c) {
  return __builtin_amdgcn_mfma_f32_16x16x32_bf16(a, b, c, 0, 0, 0);
}
// async global->LDS, 16B per lane; LDS dest must be wave-uniform base + lane*16
__device__ __forceinline__ void gload_lds16(const u16* g, u16* l) {
  __builtin_amdgcn_global_load_lds((const __attribute__((address_space(1))) void*)g,
                                   (__attribute__((address_space(3))) void*)l, 16, 0, 0);
}

// ---------------- sizes ----------------
// B=64 T=50 L=64 VOCAB=30000 EMB=300 NF=256 HID=1024 OUT=32
#define NUTT 3200          // B*T
#define EPAD 320           // E padded to mult of 32
#define NTILES 120         // (3+4+5)*10 K-step tiles of [4][256][8] bf16

// ---------------- prep: pack conv weights + cast LSTM weights to bf16 ----------------
__global__ void prep_kernel(const float* __restrict__ cw3, const float* __restrict__ cw4,
                            const float* __restrict__ cw5, const float* __restrict__ wih0,
                            const float* __restrict__ whh0, const float* __restrict__ wih1,
                            const float* __restrict__ whh1, const float* __restrict__ h2ow,
                            u16* __restrict__ Wc, u16* __restrict__ wih0b, u16* __restrict__ whh0b,
                            u16* __restrict__ wih1b, u16* __restrict__ whh1b, u16* __restrict__ Wpb) {
  const int NT = 13729792;
  for (int i = blockIdx.x * blockDim.x + threadIdx.x; i < NT; i += gridDim.x * blockDim.x) {
    if (i < 983040) {
      // Wc[T][kg][n][ke] = w_bank[n][e][j], e = kc*32+kg*8+ke, zero for e>=300
      int T = i >> 13, q = i & 8191;
      int kg = q >> 11, n = (q >> 3) & 255, ke = q & 7;
      int bank, tb; const float* cw;
      if (T < 30) { bank = 0; tb = T; cw = cw3; }
      else if (T < 70) { bank = 1; tb = T - 30; cw = cw4; }
      else { bank = 2; tb = T - 70; cw = cw5; }
      int j = tb / 10, kc = tb - 10 * (tb / 10);
      int e = kc * 32 + kg * 8 + ke, fs = 3 + bank;
      float vv = (e < 300) ? cw[(n * 300 + e) * fs + j] : 0.f;
      Wc[i] = f2bf(vv);
    } else if (i < 1114112) { int k = i - 983040; wih0b[k] = f2bf(wih0[k]); }
    else if (i < 5308416)   { int k = i - 1114112; whh0b[k] = f2bf(whh0[k]); }
    else if (i < 9502720)   { int k = i - 5308416; wih1b[k] = f2bf(wih1[k]); }
    else if (i < 13697024)  { int k = i - 9502720; whh1b[k] = f2bf(whh1[k]); }
    else { int k = i - 13697024; int c = k >> 10, kk = k & 1023; Wpb[k] = f2bf(h2ow[c * 1792 + 768 + kk]); }
  }
}

// ---------------- conv: fused embed-gather + 3-bank conv GEMM + relu-maxpool ----------------
// grid 1600, block 512 (8 waves as 2M x 4N; wave tile 64x64), BM=128 rows = 2 utterances
// LDS: A[128][328] bf16 (83968 B) + Btile[2][8192] bf16 (32768 B) = 116736 B -> 1 block/CU
// launch_bounds(512,1): do NOT request 2 waves/EU (would cap VGPR at 128 and spill acc[4][4])
// B-tile staging via global_load_lds width=16 (m193: +67% vs reg-staging on this structure);
// LDS dest is linear in tid (wave-uniform base + lane*16) so the m104 constraint holds.
__global__ __launch_bounds__(512, 1) void conv_kernel(
    const int* __restrict__ dlg, const float* __restrict__ emb, const u16* __restrict__ Wc,
    const float* __restrict__ cb3, const float* __restrict__ cb4, const float* __restrict__ cb5,
    float* __restrict__ feats) {
  extern __shared__ char smem[];
  u16* Al = (u16*)smem;                 // [128][328]
  u16* Bl = (u16*)(smem + 83968);       // [2][4][256][8]
  const int tid = threadIdx.x;
  const int u0 = blockIdx.x * 2;

  // ---- prologue: tile 0 -> Bl[0] (async, drains at the stage-A barrier) ----
  gload_lds16(Wc + tid * 8, Bl + tid * 8);
  gload_lds16(Wc + 4096 + tid * 8, Bl + 4096 + tid * 8);

  // ---- stage A: gather rows, cast to bf16, zero-pad cols 300..319 ----
  union Pack { u16 h[8]; int4 v; };
  #pragma unroll
  for (int p = 0; p < 10; ++p) {
    int task = tid + p * 512;           // 128 rows * 40 chunks
    int r = task / 40, ch = task - r * 40;
    int u = u0 + (r >> 6), tt = r & 63;
    int tok = dlg[u * 64 + tt];
    Pack pk;
    if (ch < 37) {
      const float4* s = (const float4*)(emb + tok * 300 + ch * 8);
      float4 x = s[0], y = s[1];
      pk.h[0] = f2bf(x.x); pk.h[1] = f2bf(x.y); pk.h[2] = f2bf(x.z); pk.h[3] = f2bf(x.w);
      pk.h[4] = f2bf(y.x); pk.h[5] = f2bf(y.y); pk.h[6] = f2bf(y.z); pk.h[7] = f2bf(y.w);
    } else if (ch == 37) {
      const float* s = emb + tok * 300;
      #pragma unroll
      for (int q = 0; q < 8; ++q) { int e = 296 + q; pk.h[q] = (e < 300) ? f2bf(s[e]) : (u16)0; }
    } else {
      pk.v = make_int4(0, 0, 0, 0);
    }
    *(int4*)&Al[r * 328 + ch * 8] = pk.v;
  }
  __syncthreads();   // drains lgkm (A writes) AND vmcnt (tile-0 global_load_lds)

  const int l = tid & 63, v = tid >> 6;
  const int wm = v >> 2, wn = v & 3;
  const int lr = l & 15, lg = l >> 4;
  int T = 0, bb = 0;

  for (int bank = 0; bank < 3; ++bank) {
    const int fs = 3 + bank, Lout = 62 - bank;
    f32x4 acc[4][4];
    #pragma unroll
    for (int mi = 0; mi < 4; ++mi)
      #pragma unroll
      for (int ni = 0; ni < 4; ++ni) acc[mi][ni] = (f32x4){0.f, 0.f, 0.f, 0.f};

    for (int j = 0; j < fs; ++j) {
      for (int kc = 0; kc < 10; ++kc) {
        // async-prefetch next B tile into the other buffer; lands by the barrier below
        if (T + 1 < NTILES) {
          const u16* src = Wc + (T + 1) * 8192;
          u16* dst = Bl + (bb ^ 1) * 8192;
          gload_lds16(src + tid * 8, dst + tid * 8);
          gload_lds16(src + 4096 + tid * 8, dst + 4096 + tid * 8);
        }
        // compute current tile
        const int abase = (wm * 64 + lr + j) * 328 + kc * 32 + lg * 8;
        short8 af[4]; short8 bf[4];
        #pragma unroll
        for (int mi = 0; mi < 4; ++mi) af[mi] = *(const short8*)&Al[abase + mi * 16 * 328];
        const int bbase = bb * 8192 + lg * 2048 + (wn * 64 + lr) * 8;
        #pragma unroll
        for (int ni = 0; ni < 4; ++ni) bf[ni] = *(const short8*)&Bl[bbase + ni * 128];
        #pragma unroll
        for (int mi = 0; mi < 4; ++mi)
          #pragma unroll
          for (int ni = 0; ni < 4; ++ni) acc[mi][ni] = mfma16(af[mi], bf[ni], acc[mi][ni]);
        __syncthreads();   // compiler emits s_waitcnt vmcnt(0) lgkmcnt(0) before s_barrier
        bb ^= 1; ++T;
      }
    }
    // epilogue: bias + relu + max over valid t, write feats
    const float* cb = (bank == 0) ? cb3 : ((bank == 1) ? cb4 : cb5);
    #pragma unroll
    for (int ni = 0; ni < 4; ++ni) {
      int f = wn * 64 + ni * 16 + lr;
      float bias = cb[f];
      float mx = 0.f;
      #pragma unroll
      for (int mi = 0; mi < 4; ++mi)
        #pragma unroll
        for (int r = 0; r < 4; ++r) {
          int t = mi * 16 + lg * 4 + r;
          float val = acc[mi][ni][r] + bias;
          if (t < Lout) mx = fmaxf(mx, val);
        }
      mx = fmaxf(mx, __shfl_xor(mx, 16, 64));
      mx = fmaxf(mx, __shfl_xor(mx, 32, 64));
      if (lg == 0) feats[(u0 + wm) * 768 + bank * 256 + f] = mx;
    }
  }
}

// ---------------- head_ft: head_base[t][b][c] = h2o_b[c] + feats[b*50+t] . h2o_w[c][0:768] ----------------
__global__ __launch_bounds__(256) void headft_kernel(const float* __restrict__ feats,
                                                     const float* __restrict__ h2ow,
                                                     const float* __restrict__ h2ob,
                                                     float* __restrict__ headb) {
  extern __shared__ float Wt[];  // [768][33]
  const int tid = threadIdx.x, t = blockIdx.x;
  for (int i = tid; i < 32 * 768; i += 256) {
    int c = i / 768, k = i - 768 * c;
    Wt[k * 33 + c] = h2ow[c * 1792 + k];
  }
  __syncthreads();
  const int c = tid & 31, b0r = tid >> 5;
  float acc[8];
  #pragma unroll
  for (int i = 0; i < 8; ++i) acc[i] = h2ob[c];
  for (int k4 = 0; k4 < 192; ++k4) {
    float w0 = Wt[(k4 * 4 + 0) * 33 + c], w1 = Wt[(k4 * 4 + 1) * 33 + c];
    float w2 = Wt[(k4 * 4 + 2) * 33 + c], w3 = Wt[(k4 * 4 + 3) * 33 + c];
    #pragma unroll
    for (int i = 0; i < 8; ++i) {
      int b = b0r + 8 * i;
      float4 fv = *(const float4*)&feats[(b * 50 + t) * 768 + k4 * 4];
      acc[i] += fv.x * w0 + fv.y * w1 + fv.z * w2 + fv.w * w3;
    }
  }
  #pragma unroll
  for (int i = 0; i < 8; ++i) headb[t * 2048 + (b0r + 8 * i) * 32 + c] = acc[i];
}

// ---------------- LSTM step A: pred(t-1) [redundant per WG] + layer0 gates/state + part1=h1@whh1+b1 ----------------
// grid 128 (= 2 b-halves x 64 hu-groups of 16), block 256 (4 waves: mi=v&1, q2=v>>1)
__global__ __launch_bounds__(256) void lstmA_kernel(
    const int t, const u16* __restrict__ wih0b, const u16* __restrict__ whh0b,
    const u16* __restrict__ whh1b, const u16* __restrict__ Wpb,
    const float* __restrict__ b0g, const float* __restrict__ b1g, const float* __restrict__ headb,
    const u16* __restrict__ nh1prv, const u16* __restrict__ nh0prv,
    u16* __restrict__ nh0cur, float* __restrict__ c0g, float* __restrict__ part1,
    float* __restrict__ dout) {
  __shared__ u16 pl[32 * 40];
  __shared__ float gl[2048];
  const int tid = threadIdx.x, l = tid & 63, v = tid >> 6;
  const int lr = l & 15, lg = l >> 4;
  const int w = blockIdx.x, half = w >> 6, hu0 = (w & 63) << 4;
  const int mi = v & 1, q2 = v >> 1;
  const int rowb = half * 32 + mi * 16;
  const int n0 = (q2 * 2) * 1024 + hu0 + lr, n1 = n0 + 1024;

  // J1 (pred for this b-half) + J3 (part1 = h1 @ whh1 + b1), merged K-loop over nh1(t-1)
  float bb0 = b1g[n0], bb1 = b1g[n1];
  f32x4 acc3a = {bb0, bb0, bb0, bb0}, acc3b = {bb1, bb1, bb1, bb1};
  f32x4 accP = {0.f, 0.f, 0.f, 0.f};
  if (t > 0) {
    const u16* Ar = nh1prv + (rowb + lr) * 1024 + lg * 8;
    const u16* BrP = Wpb + (q2 * 16 + lr) * 1024 + lg * 8;
    const u16* B3a = whh1b + n0 * 1024 + lg * 8;
    const u16* B3b = whh1b + n1 * 1024 + lg * 8;
    #pragma unroll 4
    for (int k = 0; k < 1024; k += 32) {
      short8 a = *(const short8*)(Ar + k);
      accP = mfma16(a, *(const short8*)(BrP + k), accP);
      acc3a = mfma16(a, *(const short8*)(B3a + k), acc3a);
      acc3b = mfma16(a, *(const short8*)(B3b + k), acc3b);
    }
  }
  {
    int rb = rowb + lg * 4;
    #pragma unroll
    for (int r = 0; r < 4; ++r) {
      part1[(rb + r) * 4096 + n0] = acc3a[r];
      part1[(rb + r) * 4096 + n1] = acc3b[r];
    }
  }
  if (t > 0) {
    int cc = q2 * 16 + lr, rb = rowb + lg * 4;
    #pragma unroll
    for (int r = 0; r < 4; ++r) {
      float x = accP[r] + headb[(t - 1) * 2048 + (rb + r) * 32 + cc];
      float p = sigm(x);
      pl[(mi * 16 + lg * 4 + r) * 40 + cc] = f2bf(p);
      if ((w & 63) == 0) dout[(rb + r) * 1600 + (t - 1) * 32 + cc] = p;
    }
  }
  __syncthreads();

  // J2: layer-0 gates
  float ba = b0g[n0], bbq = b0g[n1];
  f32x4 g0a = {ba, ba, ba, ba}, g0b = {bbq, bbq, bbq, bbq};
  if (t > 0) {
    short8 ap = *(const short8*)&pl[(mi * 16 + lr) * 40 + lg * 8];
    g0a = mfma16(ap, *(const short8*)(wih0b + n0 * 32 + lg * 8), g0a);
    g0b = mfma16(ap, *(const short8*)(wih0b + n1 * 32 + lg * 8), g0b);
    const u16* Ar = nh0prv + (rowb + lr) * 1024 + lg * 8;
    const u16* B0a = whh0b + n0 * 1024 + lg * 8;
    const u16* B0b = whh0b + n1 * 1024 + lg * 8;
    #pragma unroll 4
    for (int k = 0; k < 1024; k += 32) {
      short8 a = *(const short8*)(Ar + k);
      g0a = mfma16(a, *(const short8*)(B0a + k), g0a);
      g0b = mfma16(a, *(const short8*)(B0b + k), g0b);
    }
  }
  #pragma unroll
  for (int r = 0; r < 4; ++r) {
    int bp = mi * 16 + lg * 4 + r;
    gl[(q2 * 2) * 512 + bp * 16 + lr] = g0a[r];
    gl[(q2 * 2 + 1) * 512 + bp * 16 + lr] = g0b[r];
  }
  __syncthreads();

  #pragma unroll
  for (int p = 0; p < 2; ++p) {
    int idx = tid + p * 256;
    int bp = idx >> 4, hu = idx & 15;
    float gi = gl[idx], gf = gl[512 + idx], gg = gl[1024 + idx], go = gl[1536 + idx];
    int hidx = (half * 32 + bp) * 1024 + hu0 + hu;
    float cold = (t > 0) ? c0g[hidx] : 0.f;
    float c2 = sigm(gf) * cold + sigm(gi) * tanh_(gg);
    float h2 = sigm(go) * tanh_(c2);
    c0g[hidx] = c2;
    nh0cur[hidx] = f2bf(h2);
  }
}

// ---------------- LSTM step B: layer1 gates/state (g1 = part1 + nh0 @ wih1) ----------------
__global__ __launch_bounds__(256) void lstmB_kernel(
    const int t, const u16* __restrict__ wih1b, const float* __restrict__ part1,
    const u16* __restrict__ nh0cur, u16* __restrict__ nh1cur, float* __restrict__ c1g) {
  __shared__ float gl[2048];
  const int tid = threadIdx.x, l = tid & 63, v = tid >> 6;
  const int lr = l & 15, lg = l >> 4;
  const int w = blockIdx.x, half = w >> 6, hu0 = (w & 63) << 4;
  const int mi = v & 1, q2 = v >> 1;
  const int rowb = half * 32 + mi * 16;
  const int n0 = (q2 * 2) * 1024 + hu0 + lr, n1 = n0 + 1024;

  f32x4 acc0, acc1;
  {
    int rb = rowb + lg * 4;
    #pragma unroll
    for (int r = 0; r < 4; ++r) {
      acc0[r] = part1[(rb + r) * 4096 + n0];
      acc1[r] = part1[(rb + r) * 4096 + n1];
    }
  }
  const u16* Ar = nh0cur + (rowb + lr) * 1024 + lg * 8;
  const u16* Ba = wih1b + n0 * 1024 + lg * 8;
  const u16* Bb = wih1b + n1 * 1024 + lg * 8;
  #pragma unroll 4
  for (int k = 0; k < 1024; k += 32) {
    short8 a = *(const short8*)(Ar + k);
    acc0 = mfma16(a, *(const short8*)(Ba + k), acc0);
    acc1 = mfma16(a, *(const short8*)(Bb + k), acc1);
  }
  #pragma unroll
  for (int r = 0; r < 4; ++r) {
    int bp = mi * 16 + lg * 4 + r;
    gl[(q2 * 2) * 512 + bp * 16 + lr] = acc0[r];
    gl[(q2 * 2 + 1) * 512 + bp * 16 + lr] = acc1[r];
  }
  __syncthreads();
  #pragma unroll
  for (int p = 0; p < 2; ++p) {
    int idx = tid + p * 256;
    int bp = idx >> 4, hu = idx & 15;
    float gi = gl[idx], gf = gl[512 + idx], gg = gl[1024 + idx], go = gl[1536 + idx];
    int hidx = (half * 32 + bp) * 1024 + hu0 + hu;
    float cold = (t > 0) ? c1g[hidx] : 0.f;
    float c2 = sigm(gf) * cold + sigm(gi) * tanh_(gg);
    float h2 = sigm(go) * tanh_(c2);
    c1g[hidx] = c2;
    nh1cur[hidx] = f2bf(h2);
  }
}

// ---------------- final pred (t=49) ----------------
__global__ __launch_bounds__(256) void predfin_kernel(const u16* __restrict__ nh1,
                                                      const u16* __restrict__ Wpb,
                                                      const float* __restrict__ headb,
                                                      float* __restrict__ dout) {
  const int tid = threadIdx.x, l = tid & 63, v = tid >> 6;
  const int lr = l & 15, lg = l >> 4;
  const int half = blockIdx.x;
  const int mi = v & 1, ni = v >> 1;
  const int rowb = half * 32 + mi * 16;
  f32x4 acc = {0.f, 0.f, 0.f, 0.f};
  const u16* Ar = nh1 + (rowb + lr) * 1024 + lg * 8;
  const u16* Br = Wpb + (ni * 16 + lr) * 1024 + lg * 8;
  #pragma unroll 4
  for (int k = 0; k < 1024; k += 32)
    acc = mfma16(*(const short8*)(Ar + k), *(const short8*)(Br + k), acc);
  int cc = ni * 16 + lr, rb = rowb + lg * 4;
  #pragma unroll
  for (int r = 0; r < 4; ++r) {
    float x = acc[r] + headb[49 * 2048 + (rb + r) * 32 + cc];
    dout[(rb + r) * 1600 + 49 * 32 + cc] = sigm(x);
  }
}

extern "C" void kernel_launch(void* const* d_in, const int* in_sizes, int n_in,
                              void* d_out, int out_size, void* d_ws, size_t ws_size,
                              hipStream_t stream) {
  const int* dlg = (const int*)d_in[0];
  const float* emb = (const float*)d_in[1];
  const float* cw3 = (const float*)d_in[2];
  const float* cb3 = (const float*)d_in[3];
  const float* cw4 = (const float*)d_in[4];
  const float* cb4 = (const float*)d_in[5];
  const float* cw5 = (const float*)d_in[6];
  const float* cb5 = (const float*)d_in[7];
  const float* wih0 = (const float*)d_in[8];
  const float* whh0 = (const float*)d_in[9];
  const float* b0 = (const float*)d_in[10];
  const float* wih1 = (const float*)d_in[11];
  const float* whh1 = (const float*)d_in[12];
  const float* b1 = (const float*)d_in[13];
  const float* h2ow = (const float*)d_in[14];
  const float* h2ob = (const float*)d_in[15];
  float* dout = (float*)d_out;
  char* ws = (char*)d_ws;

  u16* Wc    = (u16*)(ws + 0);
  u16* wih0b = (u16*)(ws + 1966080);
  u16* whh0b = (u16*)(ws + 2228224);
  u16* wih1b = (u16*)(ws + 10616832);
  u16* whh1b = (u16*)(ws + 19005440);
  u16* Wpb   = (u16*)(ws + 27394048);
  float* feats = (float*)(ws + 27459584);
  float* headb = (float*)(ws + 37289984);
  u16* nh0   = (u16*)(ws + 37699584);   // [2][64*1024]
  u16* nh1   = (u16*)(ws + 37961728);   // [2][64*1024]
  float* c0  = (float*)(ws + 38223872);
  float* c1  = (float*)(ws + 38486016);
  float* part1 = (float*)(ws + 38748160);

  hipFuncSetAttribute((const void*)conv_kernel, hipFuncAttributeMaxDynamicSharedMemorySize, 116736);
  hipFuncSetAttribute((const void*)headft_kernel, hipFuncAttributeMaxDynamicSharedMemorySize, 101376);

  prep_kernel<<<dim3(2048), dim3(256), 0, stream>>>(cw3, cw4, cw5, wih0, whh0, wih1, whh1, h2ow,
                                                    Wc, wih0b, whh0b, wih1b, whh1b, Wpb);
  conv_kernel<<<dim3(1600), dim3(512), 116736, stream>>>(dlg, emb, Wc, cb3, cb4, cb5, feats);
  headft_kernel<<<dim3(50), dim3(256), 101376, stream>>>(feats, h2ow, h2ob, headb);

  for (int t = 0; t < 50; ++t) {
    const int cur = t & 1, prv = cur ^ 1;
    lstmA_kernel<<<dim3(128), dim3(256), 0, stream>>>(
        t, wih0b, whh0b, whh1b, Wpb, b0, b1, headb,
        nh1 + prv * 65536, nh0 + prv * 65536, nh0 + cur * 65536, c0, part1, dout);
    lstmB_kernel<<<dim3(128), dim3(256), 0, stream>>>(
        t, wih1b, part1, nh0 + cur * 65536, nh1 + cur * 65536, c1);
  }
  predfin_kernel<<<dim3(2), dim3(256), 0, stream>>>(nh1 + 65536, Wpb, headb, dout);
}